// Round 1
// baseline (118.378 us; speedup 1.0000x reference)
//
#include <hip/hip_runtime.h>

#define DD 96
#define HH 240
#define WW 320
#define NPIX (HH * WW)
#define NCELLS (DD * DD * DD)
#define N_STEPS 191
#define TRUNC_V 100.0f

// Dense winner grid: for each cell, the LARGEST loc index that scattered into
// it (== "last update wins", matching numpy/XLA sequential scatter), or -1 if
// empty. occ == (winner >= 0). sdf/color/normal are gathered back through the
// winner index, so duplicates stay self-consistent. 3.5 MB, L2-resident.
__device__ int g_winner[NCELLS];

__global__ void init_winner_k() {
    int i = blockIdx.x * blockDim.x + threadIdx.x;
    if (i < NCELLS) g_winner[i] = -1;
}

__global__ void scatter_k(const int* __restrict__ locs, int n) {
    int i = blockIdx.x * blockDim.x + threadIdx.x;
    if (i >= n) return;
    int x = locs[i * 4 + 0];
    int y = locs[i * 4 + 1];
    int z = locs[i * 4 + 2];
    int b = locs[i * 4 + 3];
    int lin = ((b * DD + x) * DD + y) * DD + z;
    atomicMax(&g_winner[lin], i);  // max index == last sequential update
}

__global__ __launch_bounds__(256) void raycast_k(
    const float* __restrict__ sdf_vals,
    const float* __restrict__ col_vals,
    const float* __restrict__ nrm_vals,
    const float* __restrict__ vm,    // 4x4 row-major (B=1)
    const float* __restrict__ intr,  // fx fy mx my
    float* __restrict__ out)
{
    // Keep mul+add separate so positions match the reference's FP op order
    // (a contracted FMA can flip round-to-nearest at cell boundaries).
#pragma clang fp contract(off)
    int pid = blockIdx.x * blockDim.x + threadIdx.x;
    if (pid >= NPIX) return;
    int w = pid % WW;
    int h = pid / WW;

    float fx = intr[0], fy = intr[1], mx = intr[2], my = intr[3];
    float dx = ((float)w - mx) / fx;
    float dy = ((float)h - my) / fy;
    float dz = 1.0f;
    float nrm = sqrtf((dx * dx + dy * dy) + (dz * dz));
    dx = dx / nrm;
    dy = dy / nrm;
    dz = dz / nrm;

    float r00 = vm[0], r01 = vm[1], r02 = vm[2],  t0x = vm[3];
    float r10 = vm[4], r11 = vm[5], r12 = vm[6],  t0y = vm[7];
    float r20 = vm[8], r21 = vm[9], r22 = vm[10], t0z = vm[11];

    float dwx = (r00 * dx + r01 * dy) + r02 * dz;
    float dwy = (r10 * dx + r11 * dy) + r12 * dz;
    float dwz = (r20 * dx + r21 * dy) + r22 * dz;

    auto sample = [&](float t, float& sdf, bool& occ, int& widx) {
        float px = t0x + t * dwx;
        float py = t0y + t * dwy;
        float pz = t0z + t * dwz;
        int ix = (int)rintf(px);   // round-half-to-even, matches jnp.round
        int iy = (int)rintf(py);
        int iz = (int)rintf(pz);
        bool inb = (ix >= 0) & (ix < DD) & (iy >= 0) & (iy < DD) &
                   (iz >= 0) & (iz < DD);
        widx = -1;
        if (inb) {
            int lin = (ix * DD + iy) * DD + iz;  // b = 0
            widx = g_winner[lin];
        }
        occ = widx >= 0;
        sdf = occ ? sdf_vals[widx] : TRUNC_V;
    };

    bool hit = false;
    float depth = 0.0f;
    float c0 = 0.0f, c1 = 0.0f, c2 = 0.0f;
    float n0 = 0.0f, n1 = 0.0f, n2 = 0.0f;

    float psdf; bool pocc; int wtmp;
    sample(0.5f, psdf, pocc, wtmp);

    for (int i = 0; i < N_STEPS; ++i) {
        float t = 0.5f + 0.5f * (float)(i + 1);
        float sdf; bool occ; int widx;
        sample(t, sdf, occ, widx);
        if (pocc & occ & (psdf > 0.0f) & (sdf <= 0.0f) & (psdf < 1.0f)) {
            float alpha = psdf / ((psdf - sdf) + 1e-8f);
            depth = (t - 0.5f) + alpha * 0.5f;
            c0 = col_vals[widx * 3 + 0];
            c1 = col_vals[widx * 3 + 1];
            c2 = col_vals[widx * 3 + 2];
            n0 = nrm_vals[widx * 3 + 0];
            n1 = nrm_vals[widx * 3 + 1];
            n2 = nrm_vals[widx * 3 + 2];
            hit = true;
            break;  // 'new' can never fire again once hit
        }
        psdf = sdf;
        pocc = occ;
    }
    (void)hit;

    out[pid * 3 + 0] = c0;                 // color  (B,H,W,3)
    out[pid * 3 + 1] = c1;
    out[pid * 3 + 2] = c2;
    out[NPIX * 3 + pid] = depth;           // depth  (B,H,W)
    out[NPIX * 4 + pid * 3 + 0] = n0;      // normal (B,H,W,3)
    out[NPIX * 4 + pid * 3 + 1] = n1;
    out[NPIX * 4 + pid * 3 + 2] = n2;
}

extern "C" void kernel_launch(void* const* d_in, const int* in_sizes, int n_in,
                              void* d_out, int out_size, void* d_ws, size_t ws_size,
                              hipStream_t stream) {
    const int*   locs     = (const int*)d_in[0];
    const float* sdf_vals = (const float*)d_in[1];
    const float* col_vals = (const float*)d_in[2];
    const float* nrm_vals = (const float*)d_in[3];
    const float* vm       = (const float*)d_in[4];
    const float* intr     = (const float*)d_in[5];
    int n = in_sizes[0] / 4;

    hipLaunchKernelGGL(init_winner_k, dim3((NCELLS + 255) / 256), dim3(256), 0, stream);
    hipLaunchKernelGGL(scatter_k, dim3((n + 255) / 256), dim3(256), 0, stream, locs, n);
    hipLaunchKernelGGL(raycast_k, dim3((NPIX + 255) / 256), dim3(256), 0, stream,
                       sdf_vals, col_vals, nrm_vals, vm, intr, (float*)d_out);
}

// Round 2
// 55.953 us; speedup vs baseline: 2.1157x; 2.1157x over previous
//
#include <hip/hip_runtime.h>

#define DD 96
#define HH 240
#define WW 320
#define NPIX (HH * WW)
#define NCELLS (DD * DD * DD)
#define N_STEPS 191
#define TRUNC_V 100.0f
#define CHUNK 16
#define NCHUNK 12  // 12*16 = 192 >= 191 (step 191 masked off)

// Dense grids, L2-resident (3.5 MB each).
// g_winner: largest loc index scattered into the cell (== last-update-wins,
//           matching numpy sequential scatter), or -1.
// g_sdf:    winner's sdf value, TRUNC if empty. Since scattered values are in
//           (-2,2), "occupied" == (value < TRUNC) is implied by the tests
//           psdf<1 and sdf<=0, so the hot loop needs ONE load per step.
__device__ int   g_winner[NCELLS];
__device__ float g_sdf[NCELLS];

__global__ void init_k() {
    int i = blockIdx.x * blockDim.x + threadIdx.x;
    if (i < NCELLS) { g_winner[i] = -1; g_sdf[i] = TRUNC_V; }
}

__global__ void scatter_k(const int* __restrict__ locs, int n) {
    int i = blockIdx.x * blockDim.x + threadIdx.x;
    if (i >= n) return;
    int x = locs[i * 4 + 0], y = locs[i * 4 + 1];
    int z = locs[i * 4 + 2], b = locs[i * 4 + 3];
    int lin = ((b * DD + x) * DD + y) * DD + z;
    atomicMax(&g_winner[lin], i);
}

__global__ void mat_k(const int* __restrict__ locs,
                      const float* __restrict__ sdf_vals, int n) {
    int i = blockIdx.x * blockDim.x + threadIdx.x;
    if (i >= n) return;
    int x = locs[i * 4 + 0], y = locs[i * 4 + 1];
    int z = locs[i * 4 + 2], b = locs[i * 4 + 3];
    int lin = ((b * DD + x) * DD + y) * DD + z;
    if (g_winner[lin] == i) g_sdf[lin] = sdf_vals[i];
}

__global__ __launch_bounds__(256) void raycast_k(
    const float* __restrict__ col_vals,
    const float* __restrict__ nrm_vals,
    const float* __restrict__ vm,
    const float* __restrict__ intr,
    float* __restrict__ out)
{
    // Keep mul+add separate: FMA contraction can flip round-to-nearest at
    // cell boundaries vs the numpy reference.
#pragma clang fp contract(off)
    int pid = blockIdx.x * blockDim.x + threadIdx.x;
    if (pid >= NPIX) return;
    int w = pid % WW;
    int h = pid / WW;

    float fx = intr[0], fy = intr[1], mx = intr[2], my = intr[3];
    float dx = ((float)w - mx) / fx;
    float dy = ((float)h - my) / fy;
    float dz = 1.0f;
    float nrm = sqrtf((dx * dx + dy * dy) + (dz * dz));
    dx /= nrm; dy /= nrm; dz /= nrm;

    float r00 = vm[0], r01 = vm[1], r02 = vm[2],  t0x = vm[3];
    float r10 = vm[4], r11 = vm[5], r12 = vm[6],  t0y = vm[7];
    float r20 = vm[8], r21 = vm[9], r22 = vm[10], t0z = vm[11];

    float dwx = (r00 * dx + r01 * dy) + r02 * dz;
    float dwy = (r10 * dx + r11 * dy) + r12 * dz;
    float dwz = (r20 * dx + r21 * dy) + r22 * dz;

    // sample at t: one unconditional (clamped-address) load + select
    auto sample = [&](float t) -> float {
        float px = t0x + t * dwx;
        float py = t0y + t * dwy;
        float pz = t0z + t * dwz;
        int ix = (int)rintf(px);  // RNE, matches jnp.round
        int iy = (int)rintf(py);
        int iz = (int)rintf(pz);
        bool inb = ((unsigned)ix < DD) & ((unsigned)iy < DD) & ((unsigned)iz < DD);
        int cx = min(max(ix, 0), DD - 1);
        int cy = min(max(iy, 0), DD - 1);
        int cz = min(max(iz, 0), DD - 1);
        float v = g_sdf[(cx * DD + cy) * DD + cz];
        return inb ? v : TRUNC_V;
    };

    float psdf = sample(0.5f);

    int hitI = -1;
    float hpsdf = 0.0f, hsdf = 0.0f;

    for (int c = 0; c < NCHUNK; ++c) {
        int base = c * CHUNK;
        float s[CHUNK];
#pragma unroll
        for (int j = 0; j < CHUNK; ++j) {
            int i = base + j;
            float t = 0.5f + 0.5f * (float)(i + 1);
            float sv = sample(t);
            s[j] = (i < N_STEPS) ? sv : TRUNC_V;  // mask the padding step
        }
#pragma unroll
        for (int j = 0; j < CHUNK; ++j) {
            float sv = s[j];
            bool cross = (psdf > 0.0f) & (psdf < 1.0f) & (sv <= 0.0f);
            bool newh = cross & (hitI < 0);
            if (newh) { hitI = base + j; hpsdf = psdf; hsdf = sv; }
            psdf = sv;
        }
        if (__all(hitI >= 0)) break;
    }

    float depth = 0.0f;
    float c0 = 0.0f, c1 = 0.0f, c2 = 0.0f;
    float n0 = 0.0f, n1 = 0.0f, n2 = 0.0f;
    if (hitI >= 0) {
        float t = 0.5f + 0.5f * (float)(hitI + 1);
        float px = t0x + t * dwx;
        float py = t0y + t * dwy;
        float pz = t0z + t * dwz;
        int ix = (int)rintf(px);
        int iy = (int)rintf(py);
        int iz = (int)rintf(pz);
        // hit implies sdf<=0 at this step, which required in-bounds+occupied
        int widx = g_winner[(ix * DD + iy) * DD + iz];
        float alpha = hpsdf / ((hpsdf - hsdf) + 1e-8f);
        depth = (t - 0.5f) + alpha * 0.5f;
        c0 = col_vals[widx * 3 + 0];
        c1 = col_vals[widx * 3 + 1];
        c2 = col_vals[widx * 3 + 2];
        n0 = nrm_vals[widx * 3 + 0];
        n1 = nrm_vals[widx * 3 + 1];
        n2 = nrm_vals[widx * 3 + 2];
    }

    out[pid * 3 + 0] = c0;              // color  (B,H,W,3)
    out[pid * 3 + 1] = c1;
    out[pid * 3 + 2] = c2;
    out[NPIX * 3 + pid] = depth;        // depth  (B,H,W)
    out[NPIX * 4 + pid * 3 + 0] = n0;   // normal (B,H,W,3)
    out[NPIX * 4 + pid * 3 + 1] = n1;
    out[NPIX * 4 + pid * 3 + 2] = n2;
}

extern "C" void kernel_launch(void* const* d_in, const int* in_sizes, int n_in,
                              void* d_out, int out_size, void* d_ws, size_t ws_size,
                              hipStream_t stream) {
    const int*   locs     = (const int*)d_in[0];
    const float* sdf_vals = (const float*)d_in[1];
    const float* col_vals = (const float*)d_in[2];
    const float* nrm_vals = (const float*)d_in[3];
    const float* vm       = (const float*)d_in[4];
    const float* intr     = (const float*)d_in[5];
    int n = in_sizes[0] / 4;

    hipLaunchKernelGGL(init_k, dim3((NCELLS + 255) / 256), dim3(256), 0, stream);
    hipLaunchKernelGGL(scatter_k, dim3((n + 255) / 256), dim3(256), 0, stream, locs, n);
    hipLaunchKernelGGL(mat_k, dim3((n + 255) / 256), dim3(256), 0, stream, locs, sdf_vals, n);
    hipLaunchKernelGGL(raycast_k, dim3((NPIX + 255) / 256), dim3(256), 0, stream,
                       col_vals, nrm_vals, vm, intr, (float*)d_out);
}

// Round 3
// 38.214 us; speedup vs baseline: 3.0977x; 1.4642x over previous
//
#include <hip/hip_runtime.h>

#define DD 96
#define HH 240
#define WW 320
#define NPIX (HH * WW)
#define NCELLS (DD * DD * DD)
#define N_STEPS 191
#define TRUNC_V 100.0f

// Padded, x-innermost SDF grid: covers ix,iy,iz in [-PAD, PDD-PAD).
// Reachable positions: |t*dw| <= 96*0.7071 => idx in [-20,116] subset [-24,119].
// Pad cells hold TRUNC => crossing tests (psdf in (0,1), sdf<=0) auto-reject
// OOB and empty cells; hot loop = 1 load, no clamps, no bound tests.
#define PAD 24
#define PDD 144
#define PCELLS (PDD * PDD * PDD)

#define SEG 4        // segments per ray (parallelism *4)
#define SEG_LEN 48   // 4*48 = 192 >= 191 (step 191 masked)

__device__ __attribute__((aligned(16))) int   g_winner[NCELLS];  // compact
__device__ __attribute__((aligned(16))) float g_sdf[PCELLS];     // padded, x-innermost

__device__ __forceinline__ int padded_lin(int x, int y, int z) {
    return ((z + PAD) * PDD + (y + PAD)) * PDD + (x + PAD);
}

__global__ void init_k() {
    int i = blockIdx.x * blockDim.x + threadIdx.x;
    if (i < PCELLS / 4)
        reinterpret_cast<float4*>(g_sdf)[i] = make_float4(TRUNC_V, TRUNC_V, TRUNC_V, TRUNC_V);
    if (i < NCELLS / 4)
        reinterpret_cast<int4*>(g_winner)[i] = make_int4(-1, -1, -1, -1);
}

__global__ void scatter_k(const int* __restrict__ locs, int n) {
    int i = blockIdx.x * blockDim.x + threadIdx.x;
    if (i >= n) return;
    int x = locs[i * 4 + 0], y = locs[i * 4 + 1], z = locs[i * 4 + 2];
    int lin = (x * DD + y) * DD + z;  // compact, b=0
    atomicMax(&g_winner[lin], i);     // max idx == last sequential update wins
}

__global__ void mat_k(const int* __restrict__ locs,
                      const float* __restrict__ sdf_vals, int n) {
    int i = blockIdx.x * blockDim.x + threadIdx.x;
    if (i >= n) return;
    int x = locs[i * 4 + 0], y = locs[i * 4 + 1], z = locs[i * 4 + 2];
    if (g_winner[(x * DD + y) * DD + z] == i)
        g_sdf[padded_lin(x, y, z)] = sdf_vals[i];
}

__global__ __launch_bounds__(256) void raycast_k(
    const float* __restrict__ col_vals,
    const float* __restrict__ nrm_vals,
    const float* __restrict__ vm,
    const float* __restrict__ intr,
    float* __restrict__ out)
{
    // Keep mul+add separate: FMA contraction can flip round-to-nearest at
    // cell boundaries vs the numpy reference.
#pragma clang fp contract(off)
    int tid = blockIdx.x * blockDim.x + threadIdx.x;   // NPIX*SEG threads
    int pid = tid >> 2;
    int seg = tid & 3;
    int w = pid % WW;
    int h = pid / WW;

    float fx = intr[0], fy = intr[1], mx = intr[2], my = intr[3];
    float dx = ((float)w - mx) / fx;
    float dy = ((float)h - my) / fy;
    float dz = 1.0f;
    float nrm = sqrtf((dx * dx + dy * dy) + (dz * dz));
    dx /= nrm; dy /= nrm; dz /= nrm;

    float r00 = vm[0], r01 = vm[1], r02 = vm[2],  t0x = vm[3];
    float r10 = vm[4], r11 = vm[5], r12 = vm[6],  t0y = vm[7];
    float r20 = vm[8], r21 = vm[9], r22 = vm[10], t0z = vm[11];

    float dwx = (r00 * dx + r01 * dy) + r02 * dz;
    float dwy = (r10 * dx + r11 * dy) + r12 * dz;
    float dwz = (r20 * dx + r21 * dy) + r22 * dz;

    auto sample = [&](float t) -> float {
        float px = t0x + t * dwx;
        float py = t0y + t * dwy;
        float pz = t0z + t * dwz;
        int ix = (int)rintf(px);  // RNE, matches jnp.round
        int iy = (int)rintf(py);
        int iz = (int)rintf(pz);
        return g_sdf[padded_lin(ix, iy, iz)];
    };

    int s0 = seg * SEG_LEN;  // first global step of this segment
    // psdf for step i is the sample at t = 0.5 + 0.5*i  (s0=0 -> t=0.5)
    float psdf = sample(0.5f + 0.5f * (float)s0);

    int hitI = 0x7FFFFFFF;
    float hp = 0.0f, hs = 0.0f;

    for (int c = 0; c < SEG_LEN / 16; ++c) {
        int base = s0 + c * 16;
        float s[16];
#pragma unroll
        for (int j = 0; j < 16; ++j) {
            int i = base + j;
            float t = 0.5f + 0.5f * (float)(i + 1);
            float sv = sample(t);
            s[j] = (i < N_STEPS) ? sv : TRUNC_V;  // mask padding step 191
        }
#pragma unroll
        for (int j = 0; j < 16; ++j) {
            float sv = s[j];
            bool cross = (psdf > 0.0f) & (psdf < 1.0f) & (sv <= 0.0f);
            if (cross && hitI == 0x7FFFFFFF) { hitI = base + j; hp = psdf; hs = sv; }
            psdf = sv;
        }
    }

    // reduce first-hit over the 4 segment lanes (quad = lanes 4p..4p+3)
    int key = hitI;
#pragma unroll
    for (int d = 1; d <= 2; d <<= 1) {
        int   ok = __shfl_xor(key, d);
        float op = __shfl_xor(hp, d);
        float os = __shfl_xor(hs, d);
        if (ok < key) { key = ok; hp = op; hs = os; }
    }

    if (seg != 0) return;

    float depth = 0.0f;
    float c0 = 0.0f, c1 = 0.0f, c2 = 0.0f;
    float n0 = 0.0f, n1 = 0.0f, n2 = 0.0f;
    if (key != 0x7FFFFFFF) {
        float t = 0.5f + 0.5f * (float)(key + 1);
        float px = t0x + t * dwx;
        float py = t0y + t * dwy;
        float pz = t0z + t * dwz;
        int ix = (int)rintf(px);
        int iy = (int)rintf(py);
        int iz = (int)rintf(pz);
        // hit => sdf<=0 at this cell => in-bounds & occupied
        int widx = g_winner[(ix * DD + iy) * DD + iz];
        float alpha = hp / ((hp - hs) + 1e-8f);
        depth = (t - 0.5f) + alpha * 0.5f;
        c0 = col_vals[widx * 3 + 0];
        c1 = col_vals[widx * 3 + 1];
        c2 = col_vals[widx * 3 + 2];
        n0 = nrm_vals[widx * 3 + 0];
        n1 = nrm_vals[widx * 3 + 1];
        n2 = nrm_vals[widx * 3 + 2];
    }

    out[pid * 3 + 0] = c0;              // color  (B,H,W,3)
    out[pid * 3 + 1] = c1;
    out[pid * 3 + 2] = c2;
    out[NPIX * 3 + pid] = depth;        // depth  (B,H,W)
    out[NPIX * 4 + pid * 3 + 0] = n0;   // normal (B,H,W,3)
    out[NPIX * 4 + pid * 3 + 1] = n1;
    out[NPIX * 4 + pid * 3 + 2] = n2;
}

extern "C" void kernel_launch(void* const* d_in, const int* in_sizes, int n_in,
                              void* d_out, int out_size, void* d_ws, size_t ws_size,
                              hipStream_t stream) {
    const int*   locs     = (const int*)d_in[0];
    const float* sdf_vals = (const float*)d_in[1];
    const float* col_vals = (const float*)d_in[2];
    const float* nrm_vals = (const float*)d_in[3];
    const float* vm       = (const float*)d_in[4];
    const float* intr     = (const float*)d_in[5];
    int n = in_sizes[0] / 4;

    hipLaunchKernelGGL(init_k, dim3((PCELLS / 4 + 255) / 256), dim3(256), 0, stream);
    hipLaunchKernelGGL(scatter_k, dim3((n + 255) / 256), dim3(256), 0, stream, locs, n);
    hipLaunchKernelGGL(mat_k, dim3((n + 255) / 256), dim3(256), 0, stream, locs, sdf_vals, n);
    hipLaunchKernelGGL(raycast_k, dim3((NPIX * SEG + 255) / 256), dim3(256), 0, stream,
                       col_vals, nrm_vals, vm, intr, (float*)d_out);
}

// Round 4
// 36.190 us; speedup vs baseline: 3.2711x; 1.0560x over previous
//
#include <hip/hip_runtime.h>

#define DD 96
#define HH 240
#define WW 320
#define NPIX (HH * WW)
#define NCELLS (DD * DD * DD)
#define N_STEPS 191
#define TRUNC_V 100.0f

// Padded, x-innermost CLASS grid (1 byte/cell, 144^3 = 3.0 MB, L2-resident).
// bit0 = occupied & sdf<=0 ("A"), bit1 = occupied & 0<sdf<1 ("B").
// cross at step i == B[cell(i-1)] & A[cell(i)]. Empty/OOB cells = 0.
// Reachable idx range [-20,116] subset [-24,119] => pad 24 each side.
#define PAD 24
#define PDD 144
#define PCELLS (PDD * PDD * PDD)

#define SEG 8        // segments per ray
#define SEG_LEN 24   // 8*24 = 192 >= 191 (global step 191 masked)

__device__ __attribute__((aligned(16))) int           g_winner[NCELLS];
__device__ __attribute__((aligned(16))) unsigned char g_class[PCELLS];

__device__ __forceinline__ int padded_lin(int x, int y, int z) {
    return ((z + PAD) * PDD + (y + PAD)) * PDD + (x + PAD);
}

__global__ void init_k() {
    int i = blockIdx.x * blockDim.x + threadIdx.x;
    if (i < PCELLS / 16)
        reinterpret_cast<uint4*>(g_class)[i] = make_uint4(0u, 0u, 0u, 0u);
    if (i < NCELLS / 4)
        reinterpret_cast<int4*>(g_winner)[i] = make_int4(-1, -1, -1, -1);
}

__global__ void scatter_k(const int* __restrict__ locs, int n) {
    int i = blockIdx.x * blockDim.x + threadIdx.x;
    if (i >= n) return;
    int x = locs[i * 4 + 0], y = locs[i * 4 + 1], z = locs[i * 4 + 2];
    atomicMax(&g_winner[(x * DD + y) * DD + z], i);  // last-update-wins
}

__global__ void mat_k(const int* __restrict__ locs,
                      const float* __restrict__ sdf_vals, int n) {
    int i = blockIdx.x * blockDim.x + threadIdx.x;
    if (i >= n) return;
    int x = locs[i * 4 + 0], y = locs[i * 4 + 1], z = locs[i * 4 + 2];
    if (g_winner[(x * DD + y) * DD + z] == i) {
        float s = sdf_vals[i];
        unsigned char cl = (s <= 0.0f ? 1 : 0) | ((s > 0.0f && s < 1.0f) ? 2 : 0);
        g_class[padded_lin(x, y, z)] = cl;
    }
}

__global__ __launch_bounds__(256) void raycast_k(
    const float* __restrict__ sdf_vals,
    const float* __restrict__ col_vals,
    const float* __restrict__ nrm_vals,
    const float* __restrict__ vm,
    const float* __restrict__ intr,
    float* __restrict__ out)
{
    // Keep mul+add separate: FMA contraction can flip round-to-nearest at
    // cell boundaries vs the numpy reference.
#pragma clang fp contract(off)
    int tid = blockIdx.x * blockDim.x + threadIdx.x;   // NPIX*SEG threads
    int pid = tid >> 3;
    int seg = tid & 7;
    int w = pid % WW;
    int h = pid / WW;

    float fx = intr[0], fy = intr[1], mx = intr[2], my = intr[3];
    float dx = ((float)w - mx) / fx;
    float dy = ((float)h - my) / fy;
    float dz = 1.0f;
    float nrm = sqrtf((dx * dx + dy * dy) + (dz * dz));
    dx /= nrm; dy /= nrm; dz /= nrm;

    float r00 = vm[0], r01 = vm[1], r02 = vm[2],  t0x = vm[3];
    float r10 = vm[4], r11 = vm[5], r12 = vm[6],  t0y = vm[7];
    float r20 = vm[8], r21 = vm[9], r22 = vm[10], t0z = vm[11];

    float dwx = (r00 * dx + r01 * dy) + r02 * dz;
    float dwy = (r10 * dx + r11 * dy) + r12 * dz;
    float dwz = (r20 * dx + r21 * dy) + r22 * dz;

    auto cell_of = [&](float t, int& ix, int& iy, int& iz) {
        float px = t0x + t * dwx;
        float py = t0y + t * dwy;
        float pz = t0z + t * dwz;
        ix = (int)rintf(px);  // RNE, matches jnp.round
        iy = (int)rintf(py);
        iz = (int)rintf(pz);
    };
    auto cls_at = [&](float t) -> unsigned {
        int ix, iy, iz;
        cell_of(t, ix, iy, iz);
        return (unsigned)g_class[padded_lin(ix, iy, iz)];
    };

    int s0 = seg * SEG_LEN;
    // psdf-class for global step i is the sample at t = 0.5 + 0.5*i
    unsigned pcls = cls_at(0.5f + 0.5f * (float)s0);

    // prefetch all 24 class bytes (independent loads, deep MLP)
    unsigned c[SEG_LEN];
#pragma unroll
    for (int j = 0; j < SEG_LEN; ++j) {
        int i = s0 + j;
        float t = 0.5f + 0.5f * (float)(i + 1);
        c[j] = cls_at(t);
    }
    if (seg == SEG - 1) c[SEG_LEN - 1] = 0;  // mask padding step 191

    int hitI = 0x7FFFFFFF;
#pragma unroll
    for (int j = 0; j < SEG_LEN; ++j) {
        bool cross = (((pcls >> 1) & c[j]) & 1u) != 0u;  // B[prev] & A[cur]
        if (cross && hitI == 0x7FFFFFFF) hitI = s0 + j;
        pcls = c[j];
    }

    // min-reduce first-hit step over the 8 segment lanes (lanes 8p..8p+7)
    int key = hitI;
#pragma unroll
    for (int d = 1; d <= 4; d <<= 1) {
        int ok = __shfl_xor(key, d);
        key = min(key, ok);
    }

    if (seg != 0) return;

    float depth = 0.0f;
    float c0 = 0.0f, c1 = 0.0f, c2 = 0.0f;
    float n0 = 0.0f, n1 = 0.0f, n2 = 0.0f;
    if (key != 0x7FFFFFFF) {
        // hit cell (sdf<=0 => occupied & in-bounds)
        float t = 0.5f + 0.5f * (float)(key + 1);
        int ix, iy, iz;
        cell_of(t, ix, iy, iz);
        int wi = g_winner[(ix * DD + iy) * DD + iz];
        float hs = sdf_vals[wi];
        // prev cell (0<psdf<1 => occupied & in-bounds)
        float tp = 0.5f + 0.5f * (float)key;
        int px_, py_, pz_;
        cell_of(tp, px_, py_, pz_);
        int wp = g_winner[(px_ * DD + py_) * DD + pz_];
        float hp = sdf_vals[wp];

        float alpha = hp / ((hp - hs) + 1e-8f);
        depth = (t - 0.5f) + alpha * 0.5f;
        c0 = col_vals[wi * 3 + 0];
        c1 = col_vals[wi * 3 + 1];
        c2 = col_vals[wi * 3 + 2];
        n0 = nrm_vals[wi * 3 + 0];
        n1 = nrm_vals[wi * 3 + 1];
        n2 = nrm_vals[wi * 3 + 2];
    }

    out[pid * 3 + 0] = c0;              // color  (B,H,W,3)
    out[pid * 3 + 1] = c1;
    out[pid * 3 + 2] = c2;
    out[NPIX * 3 + pid] = depth;        // depth  (B,H,W)
    out[NPIX * 4 + pid * 3 + 0] = n0;   // normal (B,H,W,3)
    out[NPIX * 4 + pid * 3 + 1] = n1;
    out[NPIX * 4 + pid * 3 + 2] = n2;
}

extern "C" void kernel_launch(void* const* d_in, const int* in_sizes, int n_in,
                              void* d_out, int out_size, void* d_ws, size_t ws_size,
                              hipStream_t stream) {
    const int*   locs     = (const int*)d_in[0];
    const float* sdf_vals = (const float*)d_in[1];
    const float* col_vals = (const float*)d_in[2];
    const float* nrm_vals = (const float*)d_in[3];
    const float* vm       = (const float*)d_in[4];
    const float* intr     = (const float*)d_in[5];
    int n = in_sizes[0] / 4;

    hipLaunchKernelGGL(init_k, dim3((NCELLS / 4 + 255) / 256), dim3(256), 0, stream);
    hipLaunchKernelGGL(scatter_k, dim3((n + 255) / 256), dim3(256), 0, stream, locs, n);
    hipLaunchKernelGGL(mat_k, dim3((n + 255) / 256), dim3(256), 0, stream, locs, sdf_vals, n);
    hipLaunchKernelGGL(raycast_k, dim3((NPIX * SEG + 255) / 256), dim3(256), 0, stream,
                       sdf_vals, col_vals, nrm_vals, vm, intr, (float*)d_out);
}